// Round 10
// baseline (358.334 us; speedup 1.0000x reference)
//
#include <hip/hip_runtime.h>
#include <hip/hip_cooperative_groups.h>
#include <stdint.h>

#define B_ 2
#define S_ 2048
#define D_ 1024
#define H_ 16
#define DQ_ 64
#define M_ 4096            // B_*S_

typedef unsigned short ushort_t;
typedef __attribute__((ext_vector_type(8))) short short8;    // 8 bf16 (4 VGPRs)
typedef __attribute__((ext_vector_type(4))) float floatx4;   // MFMA 16x16 C/D
typedef __attribute__((ext_vector_type(16))) float floatx16; // MFMA 32x32 C/D

#if __has_builtin(__builtin_amdgcn_exp2f)
#define EXP2(x) __builtin_amdgcn_exp2f(x)
#else
#define EXP2(x) exp2f(x)
#endif

__device__ __forceinline__ ushort_t f2bf(float f) {
  union { float f; uint32_t u; } v; v.f = f;
  uint32_t r = v.u + 0x7FFFu + ((v.u >> 16) & 1u);  // RNE
  return (ushort_t)(r >> 16);
}

// pack two f32 -> two bf16 (truncation; bias cancels in softmax ratio)
__device__ __forceinline__ uint32_t pk2_trunc(float a, float b) {
  union { float f; uint32_t u; } va, vb; va.f = a; vb.f = b;
  return (va.u >> 16) | (vb.u & 0xFFFF0000u);
}
__device__ __forceinline__ uint32_t pk2_rne(float a, float b) {
  return (uint32_t)f2bf(a) | ((uint32_t)f2bf(b) << 16);
}

__device__ __forceinline__ void async16(const ushort_t* g, ushort_t* l) {
  // LDS dest is wave-uniform base; HW scatters lane i at base + i*16B.
  __builtin_amdgcn_global_load_lds(
      (const __attribute__((address_space(1))) uint32_t*)g,
      (__attribute__((address_space(3))) uint32_t*)l, 16, 0, 0);
}

// ---------------- swizzled bf16 NT GEMM core, BK=64 ----------------
// C[m][n] = sum_k A[m][k] * Bt[n][k]. Block tile: (IM*32) x 128, BK=64.
// LDS rows are 64 ushorts (8 chunks of 16B); chunk c of row r holds global
// chunk c ^ (r&7)  -> ds_read_b128 readers spread over all banks.
template <int IM>
__device__ __forceinline__ void gemm_core2(const ushort_t* __restrict__ A,
                                           const ushort_t* __restrict__ Bt,
                                           ushort_t* As, ushort_t* Bs,
                                           int m0, int n0, floatx4 (&acc)[IM][4]) {
  int t = threadIdx.x, lane = t & 63, w = t >> 6;
  int wm = (w >> 1) * (IM * 16), wn = (w & 1) * 64;
  int l15 = lane & 15, quad = lane >> 4;
  int srow8 = (lane >> 3) & 7;
  int sch = ((lane & 7) ^ srow8) * 8;                  // swizzled source chunk
  const ushort_t* Ag = A + (size_t)(m0 + w * 8 + srow8) * D_ + sch;
  const ushort_t* Bg = Bt + (size_t)(n0 + w * 8 + srow8) * D_ + sch;
  for (int kt = 0; kt < D_; kt += 64) {
    __syncthreads();
#pragma unroll
    for (int c = 0; c < IM; c++)
      async16(Ag + kt + (size_t)c * 32 * D_, As + (c * 32 + w * 8) * 64);
#pragma unroll
    for (int c = 0; c < 4; c++)
      async16(Bg + kt + (size_t)c * 32 * D_, Bs + (c * 32 + w * 8) * 64);
    __syncthreads();
#pragma unroll
    for (int ks = 0; ks < 2; ks++) {
      int ch = ((ks * 4 + quad) ^ (l15 & 7)) * 8;      // swizzled read chunk
      short8 a[IM], b[4];
#pragma unroll
      for (int i = 0; i < IM; i++)
        a[i] = *(const short8*)(As + (wm + i * 16 + l15) * 64 + ch);
#pragma unroll
      for (int j = 0; j < 4; j++)
        b[j] = *(const short8*)(Bs + (wn + j * 16 + l15) * 64 + ch);
#pragma unroll
      for (int i = 0; i < IM; i++)
#pragma unroll
        for (int j = 0; j < 4; j++)
          acc[i][j] = __builtin_amdgcn_mfma_f32_16x16x32_bf16(a[i], b[j], acc[i][j], 0, 0, 0);
    }
  }
}

// ================= single fused cooperative kernel =================
// Phase 0: emb cast | W transpose | mask compaction scan
// Phase 1: QKV projection (K,V written compacted)      [grid.sync]
// Phase 2: flash attention over compacted keys          [grid.sync]
// Phase 3: output projection                            [grid.sync]
__global__ __launch_bounds__(256, 2) void k_fused(
    const float* __restrict__ emb, const float* __restrict__ Wq,
    const float* __restrict__ Wk, const float* __restrict__ Wv,
    const float* __restrict__ Wo, const int* __restrict__ mask,
    const float* __restrict__ bq, const float* __restrict__ bk,
    const float* __restrict__ bv, const float* __restrict__ bo,
    float* __restrict__ out,
    ushort_t* __restrict__ embb, ushort_t* __restrict__ Wt,
    ushort_t* __restrict__ Qb, ushort_t* __restrict__ Kb,
    ushort_t* __restrict__ Vb, ushort_t* __restrict__ Xb,
    ushort_t* __restrict__ biasC, int* __restrict__ pos,
    int* __restrict__ cntp) {
  cooperative_groups::grid_group grid = cooperative_groups::this_grid();
  __shared__ __align__(16) char smem[32768];
  int tid = threadIdx.x, nb = gridDim.x;
  int lane = tid & 63, w = tid >> 6;

  // ---------- Phase 0: prep ----------
  for (int vb = blockIdx.x; vb < 8192 + B_; vb += nb) {
    if (vb < 4096) {
      int i = (vb * 256 + tid) * 4;
      float4 v = *(const float4*)(emb + i);
      uint64_t pk = (uint64_t)f2bf(v.x) | ((uint64_t)f2bf(v.y) << 16) |
                    ((uint64_t)f2bf(v.z) << 32) | ((uint64_t)f2bf(v.w) << 48);
      *(uint64_t*)(embb + i) = pk;
    } else if (vb < 8192) {
      float (*t)[33] = (float(*)[33])smem;
      int widx = vb - 4096;
      int z = widx >> 10, tt = widx & 1023;
      const float* W = (z == 0) ? Wq : (z == 1) ? Wk : (z == 2) ? Wv : Wo;
      ushort_t* o = Wt + (size_t)z * D_ * D_;
      int k0 = (tt >> 5) * 32, n0 = (tt & 31) * 32;
      int tx = tid & 31, ty = tid >> 5;  // 32 x 8
      __syncthreads();   // guard smem reuse across vb iterations
      for (int r = 0; r < 32; r += 8)
        t[ty + r][tx] = W[(size_t)(k0 + ty + r) * D_ + n0 + tx];
      __syncthreads();
      for (int r = 0; r < 32; r += 8)
        o[(size_t)(n0 + ty + r) * D_ + k0 + tx] = f2bf(t[tx][ty + r]);
    } else if (tid < 64) {
      // order-preserving compaction: pos[s] (-1 masked), padded count, bias
      int b = vb - 8192;
      int base = 0;
      for (int c = 0; c < 32; c++) {
        int s = c * 64 + tid;
        bool m = mask[b * S_ + s] != 0;
        unsigned long long bits = __ballot(m);
        int pre = base + __popcll(bits & ((1ull << tid) - 1ull));
        pos[b * S_ + s] = m ? pre : -1;
        base += __popcll(bits);
      }
      int cnt = base;
      for (int c = 0; c < 32; c++) {
        int i = c * 64 + tid;
        biasC[b * S_ + i] = (i < cnt) ? (ushort_t)0xC180 : (ushort_t)0xCE6E;
      }
      if (tid == 0) cntp[b] = (cnt + 63) & ~63;
    }
  }
  grid.sync();

  // ---------- Phase 1: QKV projection ----------
  {
    ushort_t* As = (ushort_t*)smem;          // 128*64
    ushort_t* Bs = As + 128 * 64;            // 128*64
    for (int vb = blockIdx.x; vb < 768; vb += nb) {
      int z = vb >> 8, rem = vb & 255;
      int m0 = (rem & 31) * 128, n0 = (rem >> 5) * 128;
      const ushort_t* Bt = Wt + (size_t)z * D_ * D_;
      const float* bias = (z == 0) ? bq : (z == 1) ? bk : bv;
      floatx4 acc[4][4] = {};
      gemm_core2<4>(embb, Bt, As, Bs, m0, n0, acc);
      int wm = (w >> 1) * 64, wn = (w & 1) * 64;
      int quad = lane >> 4, l15 = lane & 15;
      float scale = 0.125f * 1.44269504f;    // 1/sqrt(DQ) * log2(e) into Q
#pragma unroll
      for (int i = 0; i < 4; i++)
#pragma unroll
        for (int j = 0; j < 4; j++) {
          int ncol = n0 + wn + j * 16 + l15;
          float bb = bias[ncol];
          int h = ncol >> 6, dq = ncol & 63;
          int m = m0 + wm + i * 16 + quad * 4;
          int b = m >> 11, s = m & (S_ - 1);
          if (z == 0) {
#pragma unroll
            for (int r = 0; r < 4; r++)
              Qb[((size_t)(b * H_ + h) * S_ + (s + r)) * DQ_ + dq] =
                  f2bf((acc[i][j][r] + bb) * scale);
          } else {
            int4 p4 = *(const int4*)(pos + b * S_ + s);
#pragma unroll
            for (int r = 0; r < 4; r++) {
              int ps = (&p4.x)[r];
              if (ps >= 0) {
                float v = acc[i][j][r] + bb;
                if (z == 1) Kb[((size_t)(b * H_ + h) * S_ + ps) * DQ_ + dq] = f2bf(v);
                else        Vb[((size_t)(b * H_ + h) * DQ_ + dq) * S_ + ps] = f2bf(v);
              }
            }
          }
        }
      __syncthreads();   // protect As/Bs before next vb staging
    }
  }
  grid.sync();

  // ---------- Phase 2: flash attention over compacted keys ----------
  // 32x32x16 MFMA; S^T = K·Q^T + bias MFMA step; P^T in regs; O^T = V^T·P^T.
  {
    ushort_t* Ks = (ushort_t*)smem;          // 64*64 [key][dq]
    ushort_t* Vs = Ks + 64 * 64;             // 64*64 [dq][key]
    int l31 = lane & 31, hi = lane >> 5;
    for (int vb = blockIdx.x; vb < 512; vb += nb) {
      int bh = vb >> 4, b = bh >> 4, h = bh & 15;
      int q0 = (vb & 15) * 128 + w * 32;
      const ushort_t* Qh = Qb + (size_t)bh * S_ * DQ_;
      const ushort_t* Kh = Kb + (size_t)bh * S_ * DQ_;
      const ushort_t* Vh = Vb + (size_t)bh * DQ_ * S_;
      const ushort_t* bbp = biasC + b * S_;
      int nk = cntp[b];

      short8 qf[4];
#pragma unroll
      for (int ks = 0; ks < 4; ks++)
        qf[ks] = *(const short8*)(Qh + (size_t)(q0 + l31) * DQ_ + ks * 16 + hi * 8);
      short8 qb_ = {};
      qb_[0] = hi ? (short)0 : (short)0x3F80;   // bf16 1.0 at k=0

      int srow8 = (lane >> 3) & 7;
      int sch = ((lane & 7) ^ srow8) * 8;
      const ushort_t* Kg1 = Kh + (size_t)(w * 8 + srow8) * DQ_ + sch;
      const ushort_t* Vg1 = Vh + (size_t)(w * 8 + srow8) * S_ + sch;

      floatx16 o[2] = {};
      float lsum = 0.0f;

      for (int k0 = 0; k0 < nk; k0 += 64) {
        __syncthreads();
        async16(Kg1 + (size_t)k0 * DQ_, Ks + w * 512);
        async16(Kg1 + (size_t)(k0 + 32) * DQ_, Ks + w * 512 + 2048);
        async16(Vg1 + k0, Vs + w * 512);
        async16(Vg1 + (size_t)32 * S_ + k0, Vs + w * 512 + 2048);
        ushort_t bv0 = bbp[k0 + l31], bv1 = bbp[k0 + 32 + l31];
        __syncthreads();

        floatx16 s0 = {}, s1 = {};
#pragma unroll
        for (int ks = 0; ks < 4; ks++) {
          int ch = ((ks * 2 + hi) ^ (l31 & 7)) * 8;
          short8 kf0 = *(const short8*)(Ks + l31 * 64 + ch);
          short8 kf1 = *(const short8*)(Ks + (32 + l31) * 64 + ch);
          s0 = __builtin_amdgcn_mfma_f32_32x32x16_bf16(kf0, qf[ks], s0, 0, 0, 0);
          s1 = __builtin_amdgcn_mfma_f32_32x32x16_bf16(kf1, qf[ks], s1, 0, 0, 0);
        }
        short8 kb0 = {}, kb1 = {};
        kb0[0] = hi ? (short)0 : (short)bv0;
        kb1[0] = hi ? (short)0 : (short)bv1;
        s0 = __builtin_amdgcn_mfma_f32_32x32x16_bf16(kb0, qb_, s0, 0, 0, 0);
        s1 = __builtin_amdgcn_mfma_f32_32x32x16_bf16(kb1, qb_, s1, 0, 0, 0);

        uint32_t pk[2][4][2];
#pragma unroll
        for (int g = 0; g < 4; g++) {
          float p0[4], p1[4];
#pragma unroll
          for (int j = 0; j < 4; j++) {
            p0[j] = EXP2(s0[g * 4 + j]);
            p1[j] = EXP2(s1[g * 4 + j]);
            lsum += p0[j] + p1[j];
          }
          pk[0][g][0] = pk2_trunc(p0[0], p0[1]); pk[0][g][1] = pk2_trunc(p0[2], p0[3]);
          pk[1][g][0] = pk2_trunc(p1[0], p1[1]); pk[1][g][1] = pk2_trunc(p1[2], p1[3]);
        }

#pragma unroll
        for (int ks = 0; ks < 4; ks++) {
          int a = ks >> 1, gb = (ks & 1) * 2;
          uint32_t pass0 = hi ? pk[a][gb][0]     : pk[a][gb + 1][0];
          uint32_t pass1 = hi ? pk[a][gb][1]     : pk[a][gb + 1][1];
          uint32_t own0  = hi ? pk[a][gb + 1][0] : pk[a][gb][0];
          uint32_t own1  = hi ? pk[a][gb + 1][1] : pk[a][gb][1];
          uint32_t recv0 = __shfl_xor(pass0, 32, 64);
          uint32_t recv1 = __shfl_xor(pass1, 32, 64);
          union { uint32_t u[4]; short8 v; } pf;
          pf.u[0] = hi ? recv0 : own0;
          pf.u[1] = hi ? recv1 : own1;
          pf.u[2] = hi ? own0 : recv0;
          pf.u[3] = hi ? own1 : recv1;
          int ch = ((ks * 2 + hi) ^ (l31 & 7)) * 8;
          short8 vf0 = *(const short8*)(Vs + l31 * 64 + ch);
          short8 vf1 = *(const short8*)(Vs + (32 + l31) * 64 + ch);
          o[0] = __builtin_amdgcn_mfma_f32_32x32x16_bf16(vf0, pf.v, o[0], 0, 0, 0);
          o[1] = __builtin_amdgcn_mfma_f32_32x32x16_bf16(vf1, pf.v, o[1], 0, 0, 0);
        }
      }

      float l = lsum + __shfl_xor(lsum, 32, 64);
      float inv = 1.0f / l;
      int q = q0 + l31;
      size_t base = (size_t)(b * S_ + q) * D_ + h * DQ_;
#pragma unroll
      for (int a = 0; a < 2; a++)
#pragma unroll
        for (int g = 0; g < 4; g++) {
          uint2 st;
          st.x = pk2_rne(o[a][4 * g] * inv, o[a][4 * g + 1] * inv);
          st.y = pk2_rne(o[a][4 * g + 2] * inv, o[a][4 * g + 3] * inv);
          *(uint2*)(Xb + base + a * 32 + g * 8 + 4 * hi) = st;
        }
      __syncthreads();   // protect Ks/Vs before next vb staging
    }
  }
  grid.sync();

  // ---------- Phase 3: output projection (fp32 out) ----------
  {
    ushort_t* As = (ushort_t*)smem;          // 64*64
    ushort_t* Bs = As + 64 * 64;             // 128*64
    const ushort_t* Wot = Wt + (size_t)3 * D_ * D_;
    for (int vb = blockIdx.x; vb < 512; vb += nb) {
      int m0 = (vb & 63) * 64, n0 = (vb >> 6) * 128;
      floatx4 acc[2][4] = {};
      gemm_core2<2>(Xb, Wot, As, Bs, m0, n0, acc);
      int wm = (w >> 1) * 32, wn = (w & 1) * 64;
      int quad = lane >> 4, l15 = lane & 15;
#pragma unroll
      for (int i = 0; i < 2; i++)
#pragma unroll
        for (int j = 0; j < 4; j++) {
          int ncol = n0 + wn + j * 16 + l15;
          float bb = bo[ncol];
          int mr = m0 + wm + i * 16 + quad * 4;
#pragma unroll
          for (int r = 0; r < 4; r++)
            out[(size_t)(mr + r) * D_ + ncol] = acc[i][j][r] + bb;
        }
      __syncthreads();
    }
  }
}

extern "C" void kernel_launch(void* const* d_in, const int* in_sizes, int n_in,
                              void* d_out, int out_size, void* d_ws, size_t ws_size,
                              hipStream_t stream) {
  const float* emb  = (const float*)d_in[0];
  const int*   mask = (const int*)d_in[1];
  const float* Wq = (const float*)d_in[2];
  const float* bq = (const float*)d_in[3];
  const float* Wk = (const float*)d_in[4];
  const float* bk = (const float*)d_in[5];
  const float* Wv = (const float*)d_in[6];
  const float* bv = (const float*)d_in[7];
  const float* Wo = (const float*)d_in[8];
  const float* bo = (const float*)d_in[9];
  float* out = (float*)d_out;

  ushort_t* embb  = (ushort_t*)d_ws;                 // 4096x1024 bf16
  ushort_t* Wt    = embb + (size_t)M_ * D_;          // 4 x 1024x1024 bf16 (transposed)
  ushort_t* Qb    = Wt + (size_t)4 * D_ * D_;        // [b,h,s,dq]  (pre-scaled)
  ushort_t* Kb    = Qb + (size_t)M_ * D_;            // [b,h,kc,dq] compacted
  ushort_t* Vb    = Kb + (size_t)M_ * D_;            // [b,h,dq,kc] compacted V^T
  ushort_t* Xb    = Vb + (size_t)M_ * D_;            // [b*s, h*dq]
  ushort_t* biasC = Xb + (size_t)M_ * D_;            // [B_][S_] bf16 bias
  int* pos        = (int*)(biasC + (size_t)B_ * S_); // [B_][S_] compaction map
  int* cntp       = pos + B_ * S_;                   // [B_] padded counts

  // co-residency-safe grid (host queries run once at graph capture)
  int bpc = 0;
  hipOccupancyMaxActiveBlocksPerMultiprocessor(&bpc, (const void*)k_fused, 256, 0);
  if (bpc < 1) bpc = 1;
  if (bpc > 4) bpc = 4;
  hipDeviceProp_t prop;
  hipGetDeviceProperties(&prop, 0);
  int grid = bpc * prop.multiProcessorCount;

  void* args[] = {
    (void*)&emb, (void*)&Wq, (void*)&Wk, (void*)&Wv, (void*)&Wo, (void*)&mask,
    (void*)&bq, (void*)&bk, (void*)&bv, (void*)&bo, (void*)&out,
    (void*)&embb, (void*)&Wt, (void*)&Qb, (void*)&Kb, (void*)&Vb, (void*)&Xb,
    (void*)&biasC, (void*)&pos, (void*)&cntp };
  hipLaunchCooperativeKernel((const void*)k_fused, dim3(grid), dim3(256),
                             args, 0, stream);
}